// Round 6
// baseline (79.660 us; speedup 1.0000x reference)
//
#include <hip/hip_runtime.h>

#define NB 8
#define C_IN 64
#define HW 65536      // 256*256
#define CF 256
#define FHW 4096      // 64*64
#define NSEG 256
#define FBLK 16       // featsum blocks per batch
#define MBLK 64       // input blocks per batch
#define TOTB 80
#define MAGIC 0x13579BDFu
#define AG __HIP_MEMORY_SCOPE_AGENT

// ws layout (floats):
// fsum     [NB][FHW]            @ 0       (32768)
// seg_part [NB][MBLK][2][NSEG]  @ 32768   (262144)
// binf_part[NB][MBLK][NSEG]     @ 294912  (131072)
// u32 flags @ 425984: p1[NB][TOTB], p2[NB][MBLK], r1[NB], ppbits[NB], bflags[NB]

__global__ __launch_bounds__(256) void fused(
    const float* __restrict__ input, const int* __restrict__ sp,
    const float* __restrict__ feat,
    float* __restrict__ fsum, float* __restrict__ seg_part,
    float* __restrict__ binf_part,
    unsigned* __restrict__ p1, unsigned* __restrict__ p2,
    unsigned* __restrict__ r1, unsigned* __restrict__ ppbits,
    unsigned* __restrict__ bflags, float* __restrict__ out) {
  __shared__ float smem[FHW + NSEG];   // 17.4 KB
  int b = blockIdx.y, e = blockIdx.x, t = threadIdx.x;

  if (e >= FBLK) {
    // ---------- input block: phase 1 (stream + histogram) ----------
    int blk = e - FBLK;
    float* bin_x = smem;
    float* bin_c = smem + NSEG;
    bin_x[t] = 0.f; bin_c[t] = 0.f;
    __syncthreads();
    int v0 = blk * 256 + t;
    const float4* in4 = (const float4*)(input + (size_t)b * C_IN * HW);
    float4 xs = make_float4(0.f, 0.f, 0.f, 0.f);
#pragma unroll
    for (int c = 0; c < C_IN; ++c) {
      float4 v = in4[(size_t)c * (HW / 4) + v0];
      xs.x += v.x; xs.y += v.y; xs.z += v.z; xs.w += v.w;
    }
    int4 sv = ((const int4*)(sp + (size_t)b * HW))[v0];
    atomicAdd(&bin_x[sv.x], xs.x); atomicAdd(&bin_c[sv.x], 1.f);
    atomicAdd(&bin_x[sv.y], xs.y); atomicAdd(&bin_c[sv.y], 1.f);
    atomicAdd(&bin_x[sv.z], xs.z); atomicAdd(&bin_c[sv.z], 1.f);
    atomicAdd(&bin_x[sv.w], xs.w); atomicAdd(&bin_c[sv.w], 1.f);
    __syncthreads();
    float* sb = seg_part + (size_t)(b * MBLK + blk) * 2 * NSEG;
    sb[t] = bin_x[t];
    sb[NSEG + t] = bin_c[t];
    __syncthreads();                    // drain stores before release
    if (t == 0) {
      __hip_atomic_store(&p1[b * TOTB + e], MAGIC, __ATOMIC_RELEASE, AG);
      while (__hip_atomic_load(&r1[b], __ATOMIC_RELAXED, AG) != MAGIC)
        __builtin_amdgcn_s_sleep(2);
    }
    __syncthreads();
    __builtin_amdgcn_fence(__ATOMIC_ACQUIRE, "agent");
    // ---------- phase 2: bilinear + feat histogram (sv still in regs) ----------
    {
      const float4* s4 = (const float4*)(fsum + (size_t)b * FHW);
      float4* d4 = (float4*)smem;
#pragma unroll
      for (int i = 0; i < 4; ++i) d4[i * 256 + t] = s4[i * 256 + t];
    }
    float* fls = smem;
    float* binf = smem + FHW;
    binf[t] = 0.f;
    __syncthreads();
    int p0 = v0 * 4;
    int y = p0 >> 8;
    float cy = (float)y * (63.0f / 255.0f);
    int iy = (int)cy; float ty = cy - (float)iy; int iy1 = min(iy + 1, 63);
    int svv[4] = {sv.x, sv.y, sv.z, sv.w};
#pragma unroll
    for (int kk = 0; kk < 4; ++kk) {
      int x = (p0 + kk) & 255;
      float cx = (float)x * (63.0f / 255.0f);
      int ix = (int)cx; float tx = cx - (float)ix; int ix1 = min(ix + 1, 63);
      float f00 = fls[iy * 64 + ix],  f10 = fls[iy1 * 64 + ix];
      float f01 = fls[iy * 64 + ix1], f11 = fls[iy1 * 64 + ix1];
      float a0 = f00 * (1.f - ty) + f10 * ty;
      float a1 = f01 * (1.f - ty) + f11 * ty;
      atomicAdd(&binf[svv[kk]], a0 * (1.f - tx) + a1 * tx);
    }
    __syncthreads();
    binf_part[(size_t)(b * MBLK + blk) * NSEG + t] = binf[t];
    __syncthreads();
    if (t == 0)
      __hip_atomic_store(&p2[b * MBLK + blk], MAGIC, __ATOMIC_RELEASE, AG);
    return;
  }

  // ---------- featsum strip e (all 256 channels of 256 px) ----------
  {
    int q = t & 63, cg = t >> 6;
    const float4* f4 = (const float4*)(feat + (size_t)b * CF * FHW);
    int col = e * 64 + q;
    float4 s = make_float4(0.f, 0.f, 0.f, 0.f);
#pragma unroll 8
    for (int c = cg; c < CF; c += 4) {
      float4 v = f4[(size_t)c * (FHW / 4) + col];
      s.x += v.x; s.y += v.y; s.z += v.z; s.w += v.w;
    }
    float4* lred = (float4*)smem;                  // [4][64] float4
    lred[cg * 64 + q] = s;
    __syncthreads();
    if (t < 64) {
      float4 a = lred[t], b1 = lred[64 + t], c1 = lred[128 + t], d = lred[192 + t];
      a.x += b1.x + c1.x + d.x; a.y += b1.y + c1.y + d.y;
      a.z += b1.z + c1.z + d.z; a.w += b1.w + c1.w + d.w;
      ((float4*)fsum)[(size_t)b * (FHW / 4) + e * 64 + t] = a;
    }
    __syncthreads();                    // drain fsum stores before release
  }
  if (e != 0) {
    if (t == 0)
      __hip_atomic_store(&p1[b * TOTB + e], MAGIC, __ATOMIC_RELEASE, AG);
    return;
  }

  // ---------- master (e == 0): barriers + finisher ----------
  if (t >= 1 && t < TOTB) {
    unsigned* f = &p1[b * TOTB + t];
    while (__hip_atomic_load(f, __ATOMIC_RELAXED, AG) != MAGIC)
      __builtin_amdgcn_s_sleep(2);
    __hip_atomic_store(f, 0u, __ATOMIC_RELAXED, AG);
  }
  __syncthreads();
  if (t == 0)
    __hip_atomic_store(&r1[b], MAGIC, __ATOMIC_RELEASE, AG);
  if (t < MBLK) {
    unsigned* f = &p2[b * MBLK + t];
    while (__hip_atomic_load(f, __ATOMIC_RELAXED, AG) != MAGIC)
      __builtin_amdgcn_s_sleep(2);
    __hip_atomic_store(f, 0u, __ATOMIC_RELAXED, AG);
  }
  __syncthreads();
  __builtin_amdgcn_fence(__ATOMIC_ACQUIRE, "agent");
  if (t == 0) __hip_atomic_store(&r1[b], 0u, __ATOMIC_RELAXED, AG);

  float* s2 = smem;            // 512
  float* sf = smem + 512;      // 256
  float* m1 = smem + 768;      // 256
  float* m2 = smem + 1024;     // 256
  float* red = smem + 1280;    // 4
  for (int u = t; u < 2 * NSEG; u += 256) {
    const float* base = seg_part + (size_t)b * MBLK * 2 * NSEG + u;
    float s = 0.f;
#pragma unroll
    for (int k = 0; k < MBLK; ++k) s += base[k * 2 * NSEG];
    s2[u] = s;
  }
  {
    const float* base = binf_part + (size_t)b * MBLK * NSEG + t;
    float s = 0.f;
#pragma unroll
    for (int k = 0; k < MBLK; ++k) s += base[k * NSEG];
    sf[t] = s;
  }
  __syncthreads();
  {
    float cnt = s2[NSEG + t];
    m1[t] = s2[t] / (cnt * 64.0f);
    m2[t] = sf[t] / (cnt * 256.0f);
  }
  __syncthreads();
  float a1 = m1[t], a2 = m2[t], acc = 0.f;
#pragma unroll 8
  for (int j = 0; j < NSEG; ++j)
    acc += fabsf(fabsf(a1 - m1[j]) - fabsf(a2 - m2[j]));
#pragma unroll
  for (int off = 32; off; off >>= 1) acc += __shfl_down(acc, off);
  if ((t & 63) == 0) red[t >> 6] = acc;
  __syncthreads();
  if (t == 0) {
    float s = red[0] + red[1] + red[2] + red[3];
    __hip_atomic_store(&ppbits[b], __float_as_uint(s), __ATOMIC_RELAXED, AG);
    __hip_atomic_store(&bflags[b], MAGIC, __ATOMIC_RELEASE, AG);
    if (b == 0) {
      float tot = s;
      for (int ob = 1; ob < NB; ++ob) {
        while (__hip_atomic_load(&bflags[ob], __ATOMIC_RELAXED, AG) != MAGIC)
          __builtin_amdgcn_s_sleep(2);
        tot += __uint_as_float(__hip_atomic_load(
            &ppbits[ob], __ATOMIC_RELAXED, AG));
        __hip_atomic_store(&bflags[ob], 0u, __ATOMIC_RELAXED, AG);
      }
      out[0] = tot / 524288.0f;  // NB * NSEG * NSEG
      __hip_atomic_store(&bflags[0], 0u, __ATOMIC_RELAXED, AG);
    }
  }
}

extern "C" void kernel_launch(void* const* d_in, const int* in_sizes, int n_in,
                              void* d_out, int out_size, void* d_ws, size_t ws_size,
                              hipStream_t stream) {
  const float* input   = (const float*)d_in[0];
  const float* feature = (const float*)d_in[1];
  const int*   sp      = (const int*)d_in[2];
  float* ws = (float*)d_ws;
  float*    fsum      = ws;
  float*    seg_part  = ws + (size_t)NB * FHW;
  float*    binf_part = seg_part + (size_t)NB * MBLK * 2 * NSEG;
  unsigned* ub        = (unsigned*)(binf_part + (size_t)NB * MBLK * NSEG);
  unsigned* p1     = ub;                      // NB*TOTB
  unsigned* p2     = p1 + NB * TOTB;          // NB*MBLK
  unsigned* r1     = p2 + NB * MBLK;          // NB
  unsigned* ppbits = r1 + NB;                 // NB
  unsigned* bflags = ppbits + NB;             // NB

  fused<<<dim3(TOTB, NB), 256, 0, stream>>>(input, sp, feature, fsum, seg_part,
                                            binf_part, p1, p2, r1, ppbits,
                                            bflags, (float*)d_out);
}

// Round 7
// 50.542 us; speedup vs baseline: 1.5761x; 1.5761x over previous
//
#include <hip/hip_runtime.h>

#define NB 8
#define C_IN 64
#define HW 65536      // 256*256
#define CF 256
#define FHW 4096      // 64*64
#define NSEG 256
#define MBLK 64       // main blocks per batch
#define MAGIC 0x13579BDFu
#define AG __HIP_MEMORY_SCOPE_AGENT

// ws layout (floats):
// fsum    [NB][FHW]            @ 0      (32768)
// seg_part[NB][MBLK][3][NSEG]  @ 32768  (393216)  0=xsum,1=cnt,2=fsum
// u32: ppbits[NB], bflags[NB]  after

// ---------- A: feature channel-sum, fully reduced to fsum[b][4096] ----------
__global__ __launch_bounds__(256) void featsum_kernel(
    const float* __restrict__ feat, float* __restrict__ fsum) {
  __shared__ float4 lred[256];          // [4][64]
  int b = blockIdx.y, e = blockIdx.x, t = threadIdx.x;
  int q = t & 63, cg = t >> 6;          // 4 channel groups, 64 ch each
  const float4* f4 = (const float4*)(feat + (size_t)b * CF * FHW);
  int col = e * 64 + q;
  float4 s = make_float4(0.f, 0.f, 0.f, 0.f);
#pragma unroll 8
  for (int c = cg; c < CF; c += 4) {
    float4 v = f4[(size_t)c * (FHW / 4) + col];
    s.x += v.x; s.y += v.y; s.z += v.z; s.w += v.w;
  }
  lred[cg * 64 + q] = s;
  __syncthreads();
  if (t < 64) {
    float4 a = lred[t], b1 = lred[64 + t], c1 = lred[128 + t], d = lred[192 + t];
    a.x += b1.x + c1.x + d.x; a.y += b1.y + c1.y + d.y;
    a.z += b1.z + c1.z + d.z; a.w += b1.w + c1.w + d.w;
    ((float4*)fsum)[(size_t)b * (FHW / 4) + e * 64 + t] = a;
  }
}

// ---------- B: input stream + bilinear + all three histograms ----------
__global__ __launch_bounds__(256) void main_kernel(
    const float* __restrict__ input, const int* __restrict__ sp,
    const float* __restrict__ fsum, float* __restrict__ seg_part) {
  __shared__ float fls[FHW];
  __shared__ float bin[3][NSEG];
  int b = blockIdx.y, blk = blockIdx.x, t = threadIdx.x;
  {
    const float4* s4 = (const float4*)(fsum + (size_t)b * FHW);
    float4* d4 = (float4*)fls;
#pragma unroll
    for (int i = 0; i < 4; ++i) d4[i * 256 + t] = s4[i * 256 + t];
  }
  bin[0][t] = 0.f; bin[1][t] = 0.f; bin[2][t] = 0.f;
  __syncthreads();

  int v0 = blk * 256 + t;
  const float4* in4 = (const float4*)(input + (size_t)b * C_IN * HW);
  float4 xs = make_float4(0.f, 0.f, 0.f, 0.f);
#pragma unroll
  for (int c = 0; c < C_IN; ++c) {
    float4 v = in4[(size_t)c * (HW / 4) + v0];
    xs.x += v.x; xs.y += v.y; xs.z += v.z; xs.w += v.w;
  }
  int4 sv = ((const int4*)(sp + (size_t)b * HW))[v0];
  atomicAdd(&bin[0][sv.x], xs.x); atomicAdd(&bin[1][sv.x], 1.f);
  atomicAdd(&bin[0][sv.y], xs.y); atomicAdd(&bin[1][sv.y], 1.f);
  atomicAdd(&bin[0][sv.z], xs.z); atomicAdd(&bin[1][sv.z], 1.f);
  atomicAdd(&bin[0][sv.w], xs.w); atomicAdd(&bin[1][sv.w], 1.f);

  int p0 = v0 * 4;
  int y = p0 >> 8;
  float cy = (float)y * (63.0f / 255.0f);
  int iy = (int)cy; float ty = cy - (float)iy; int iy1 = min(iy + 1, 63);
  int svv[4] = {sv.x, sv.y, sv.z, sv.w};
#pragma unroll
  for (int kk = 0; kk < 4; ++kk) {
    int x = (p0 + kk) & 255;
    float cx = (float)x * (63.0f / 255.0f);
    int ix = (int)cx; float tx = cx - (float)ix; int ix1 = min(ix + 1, 63);
    float f00 = fls[iy * 64 + ix],  f10 = fls[iy1 * 64 + ix];
    float f01 = fls[iy * 64 + ix1], f11 = fls[iy1 * 64 + ix1];
    float a0 = f00 * (1.f - ty) + f10 * ty;
    float a1 = f01 * (1.f - ty) + f11 * ty;
    atomicAdd(&bin[2][svv[kk]], a0 * (1.f - tx) + a1 * tx);
  }
  __syncthreads();
  float* sb = seg_part + (size_t)(b * MBLK + blk) * 3 * NSEG;
  sb[t]            = bin[0][t];
  sb[NSEG + t]     = bin[1][t];
  sb[2 * NSEG + t] = bin[2][t];
}

// ---------- C: reduce partials, means, pair sum, cross-batch finish ----------
__global__ __launch_bounds__(1024) void pairfinal_kernel(
    const float* __restrict__ seg_part,
    unsigned* __restrict__ ppbits, unsigned* __restrict__ bflags,
    float* __restrict__ out) {
  __shared__ float s3[3 * NSEG];
  __shared__ float m1[NSEG], m2[NSEG];
  __shared__ float red[16];
  int b = blockIdx.x, t = threadIdx.x;
  if (t < 3 * NSEG) {
    const float* base = seg_part + (size_t)b * MBLK * 3 * NSEG + t;
    float s = 0.f;
#pragma unroll
    for (int k = 0; k < MBLK; ++k) s += base[k * 3 * NSEG];
    s3[t] = s;
  }
  __syncthreads();
  if (t < NSEG) {
    float cnt = s3[NSEG + t];
    m1[t] = s3[t] / (cnt * 64.0f);
    m2[t] = s3[2 * NSEG + t] / (cnt * 256.0f);
  }
  __syncthreads();
  int i = t & 255, j0 = (t >> 8) * 64;
  float a1 = m1[i], a2 = m2[i], acc = 0.f;
#pragma unroll
  for (int jj = 0; jj < 64; ++jj) {
    int j = j0 + jj;
    acc += fabsf(fabsf(a1 - m1[j]) - fabsf(a2 - m2[j]));
  }
#pragma unroll
  for (int off = 32; off; off >>= 1) acc += __shfl_down(acc, off);
  if ((t & 63) == 0) red[t >> 6] = acc;
  __syncthreads();
  if (t == 0) {
    float s = 0.f;
#pragma unroll
    for (int w = 0; w < 16; ++w) s += red[w];
    __hip_atomic_store(&ppbits[b], __float_as_uint(s), __ATOMIC_RELAXED, AG);
    __hip_atomic_store(&bflags[b], MAGIC, __ATOMIC_RELEASE, AG);
    if (b == 0) {
      float tot = s;
      for (int ob = 1; ob < NB; ++ob) {
        while (__hip_atomic_load(&bflags[ob], __ATOMIC_ACQUIRE, AG) != MAGIC)
          __builtin_amdgcn_s_sleep(2);
        tot += __uint_as_float(__hip_atomic_load(
            &ppbits[ob], __ATOMIC_RELAXED, AG));
        __hip_atomic_store(&bflags[ob], 0u, __ATOMIC_RELAXED, AG);
      }
      out[0] = tot / 524288.0f;  // NB * NSEG * NSEG
      __hip_atomic_store(&bflags[0], 0u, __ATOMIC_RELAXED, AG);
    }
  }
}

extern "C" void kernel_launch(void* const* d_in, const int* in_sizes, int n_in,
                              void* d_out, int out_size, void* d_ws, size_t ws_size,
                              hipStream_t stream) {
  const float* input   = (const float*)d_in[0];
  const float* feature = (const float*)d_in[1];
  const int*   sp      = (const int*)d_in[2];
  float* ws = (float*)d_ws;
  float*    fsum     = ws;
  float*    seg_part = ws + (size_t)NB * FHW;
  unsigned* ppbits   = (unsigned*)(seg_part + (size_t)NB * MBLK * 3 * NSEG);
  unsigned* bflags   = ppbits + NB;

  featsum_kernel<<<dim3(16, NB), 256, 0, stream>>>(feature, fsum);
  main_kernel<<<dim3(MBLK, NB), 256, 0, stream>>>(input, sp, fsum, seg_part);
  pairfinal_kernel<<<dim3(NB), 1024, 0, stream>>>(seg_part, ppbits, bflags,
                                                  (float*)d_out);
}